// Round 3
// baseline (163.481 us; speedup 1.0000x reference)
//
#include <hip/hip_runtime.h>
#include <stdint.h>

// ModulatedConv (StyleGAN2 up-conv): B=8, Cin=Cout=512, K=3, 32x32 -> 64x64, fp32 I/O.
// Pipeline (3 kernels):
//   K1 k_prep:  blocks 0..511  = dcoef + Wm[b][tap][o][i] bf16 (37.75 MB), block per o
//               blocks 512..1023 = XT[b][hw][i] bf16 (8.39 MB) transpose
//   K2 k_gemm:  tap fused into M: per batch GEMM M=4608,N=1024,K=512. 128x256 tile,
//               BK=32, 48KB LDS -> 2 blocks/CU (cross-block stall hiding), T2 swizzle,
//               issue-early staging + cheap drain, raw barriers, setprio.
//   K3 k_fir:   parity scatter + separable 4x4 FIR per (b,o), 512 thr, padded V

#define DI __device__ __forceinline__

typedef __bf16 bf16x8 __attribute__((ext_vector_type(8)));
typedef float f32x4 __attribute__((ext_vector_type(4)));

DI float bf2f(ushort u) { union { uint32_t i; float f; } v; v.i = ((uint32_t)u) << 16; return v.f; }
DI ushort f2bf(float f) {
  union { float f; uint32_t i; } v; v.f = f;
  uint32_t x = v.i;
  return (ushort)((x + 0x7FFFu + ((x >> 16) & 1u)) >> 16);  // RNE
}

#define GAIN (1.0f / 1536.0f)  // 1/sqrt(512*512*9)

// ---------------- K1: fused weight-prep (blocks 0..511) + x-transpose (512..1023) -------
__global__ __launch_bounds__(256) void k_prep(const float* __restrict__ w,
                                              const float* __restrict__ styles,
                                              const float* __restrict__ x,
                                              ushort* __restrict__ Wm,
                                              ushort* __restrict__ xt) {
  __shared__ union {
    struct { float ss[4096]; float dc[8]; float wred[4][8]; } wp;
    float tl[32][257];
  } sm;
  const int t = threadIdx.x;
  if (blockIdx.x < 512) {
    // ---- weight prep: block per o. Thread t owns i = 2t, 2t+1. ----
    const int o = blockIdx.x;
#pragma unroll
    for (int j = 0; j < 4; j++) {
      const int idx = (t + j * 256) * 4;
      *(float4*)&sm.wp.ss[idx] = *(const float4*)&styles[idx];
    }
    float wreg[18];
    const float* wp_ = w + o * 4608 + t * 18;
#pragma unroll
    for (int k = 0; k < 9; k++) {
      float2 v2 = *(const float2*)(wp_ + 2 * k);
      wreg[2 * k] = v2.x;
      wreg[2 * k + 1] = v2.y;
    }
    float q0 = 0.f, q1 = 0.f;
#pragma unroll
    for (int k = 0; k < 9; k++) {
      q0 += wreg[k] * wreg[k];
      q1 += wreg[9 + k] * wreg[9 + k];
    }
    __syncthreads();  // ss ready
    float pb[8];
#pragma unroll
    for (int b = 0; b < 8; b++) {
      float s0 = sm.wp.ss[b * 512 + 2 * t] + 1.0f;
      float s1 = sm.wp.ss[b * 512 + 2 * t + 1] + 1.0f;
      pb[b] = s0 * s0 * q0 + s1 * s1 * q1;
    }
#pragma unroll
    for (int b = 0; b < 8; b++)
#pragma unroll
      for (int off = 32; off > 0; off >>= 1) pb[b] += __shfl_down(pb[b], off, 64);
    const int wid = t >> 6, lane = t & 63;
    if (lane == 0) {
#pragma unroll
      for (int b = 0; b < 8; b++) sm.wp.wred[wid][b] = pb[b];
    }
    __syncthreads();
    if (t < 8)
      sm.wp.dc[t] = rsqrtf((sm.wp.wred[0][t] + sm.wp.wred[1][t] + sm.wp.wred[2][t] + sm.wp.wred[3][t]) *
                               (GAIN * GAIN) + 1e-8f);
    __syncthreads();
#pragma unroll
    for (int b = 0; b < 8; b++) {
      const float d = sm.wp.dc[b];
      const float s0 = GAIN * (sm.wp.ss[b * 512 + 2 * t] + 1.0f) * d;
      const float s1 = GAIN * (sm.wp.ss[b * 512 + 2 * t + 1] + 1.0f) * d;
      ushort* base = Wm + ((size_t)(b * 9) * 512 + o) * 512 + 2 * t;
#pragma unroll
      for (int tap = 0; tap < 9; tap++) {
        ushort2 val = make_ushort2(f2bf(wreg[tap] * s0), f2bf(wreg[9 + tap] * s1));
        *(ushort2*)(base + (size_t)tap * 262144) = val;
      }
    }
  } else {
    // ---- x transpose: tile 32 i x 256 hw ----
    const int idx = blockIdx.x - 512;
    const int hw0 = (idx & 3) * 256, i0 = ((idx >> 2) & 15) * 32, b = idx >> 6;
    const float* xb = x + b * (512 * 1024);
#pragma unroll
    for (int p = 0; p < 8; p++) {
      const int r = p * 4 + (t >> 6);
      const int c4 = (t & 63) * 4;
      float4 v = *(const float4*)&xb[(i0 + r) * 1024 + hw0 + c4];
      sm.tl[r][c4] = v.x; sm.tl[r][c4 + 1] = v.y; sm.tl[r][c4 + 2] = v.z; sm.tl[r][c4 + 3] = v.w;
    }
    __syncthreads();
    ushort* xtb = xt + b * (1024 * 512);
#pragma unroll
    for (int p = 0; p < 8; p++) {
      const int hw = p * 32 + (t >> 3);
      const int i4 = (t & 7) * 4;
      ushort4 v = make_ushort4(f2bf(sm.tl[i4][hw]), f2bf(sm.tl[i4 + 1][hw]),
                               f2bf(sm.tl[i4 + 2][hw]), f2bf(sm.tl[i4 + 3][hw]));
      *(ushort4*)&xtb[(hw0 + hw) * 512 + i0 + i4] = v;
    }
  }
}

// ---------------- K2: 8 x GEMM (M=4608,N=1024,K=512), C[b] = Wm[b] @ XT[b]^T ------------
// 128x256 tile, BK=32, 8 waves (2M x 4N), per-wave 64x64 (acc[4][4] = 64 VGPR).
// LDS 48 KiB = 2dbuf x { A[128][32k]=8KB , B[256][32k]=16KB }, row = 64 B = 4 slots.
// __launch_bounds__(512,4) caps 128 VGPR -> 2 blocks/CU: barrier stalls of one block
// overlap the other block's MFMA (m114 mechanism).
// Swizzle (rule 21, both-sides): LDS linear dest; source slot = (l&3)^((l>>3)&3);
// ds_read slot = lq ^ ((row>>1)&3) -> 2-way bank aliasing (free, m136).
// Per K-tile: { issue 3 GLL for t+1 (issue-early: full MFMA phase of latency cover) |
//   8 ds_read_b128 | setprio(1) 16 MFMA setprio(0) | vmcnt(0) (cheap drain) | BAR }.
__global__ __launch_bounds__(512, 4) void k_gemm(const ushort* __restrict__ A,
                                                 const ushort* __restrict__ Bt,
                                                 ushort* __restrict__ C) {
  __shared__ __attribute__((aligned(128))) char smem[49152];
  const int id = blockIdx.x;
  const int batch = id & 7;        // XCD affinity: XT slab (1 MB) stays L2-resident
  const int rem = id >> 3;         // 0..143: mt-major
  const int mt = rem >> 2, nt = rem & 3;
  const int m0 = mt * 128, n0 = nt * 256;
  const ushort* Ag = A + (size_t)batch * (4608 * 512);
  const ushort* Bg = Bt + (size_t)batch * (1024 * 512);
  ushort* Cg = C + (size_t)batch * (4608 * 1024);

  const int tid = threadIdx.x;
  const int w = tid >> 6, lane = tid & 63;
  const int wm = w >> 2, wn = w & 3;            // wave tile: rows wm*64, cols wn*64
  const int lq = lane >> 4, l15 = lane & 15;

  // ---- staging: 24 GLL/block (A chunks 0-7, B chunks 0-15), 3 per wave ----
  const int srow = lane >> 2;                       // row within 16-row chunk
  const int sslot = (lane & 3) ^ ((lane >> 3) & 3); // inverse-swizzled source slot
  const char* gsrc[3];
  int ldst[3];
#pragma unroll
  for (int q = 0; q < 3; ++q) {
    const int idx = 3 * w + q;
    const bool isA = idx < 8;
    const int ch = isA ? idx : idx - 8;
    const int grow = (isA ? m0 : n0) + ch * 16 + srow;
    gsrc[q] = (const char*)(isA ? Ag : Bg) + (size_t)grow * 1024 + sslot * 16;
    ldst[q] = (isA ? 0 : 8192) + ch * 1024;
  }

#define GLL(srcp, dstp)                                                                     \
  __builtin_amdgcn_global_load_lds((const __attribute__((address_space(1))) void*)(srcp),   \
                                   (__attribute__((address_space(3))) void*)(dstp), 16, 0, 0)
#define ISSUE(buf, kt)                                              \
  do {                                                              \
    _Pragma("unroll")                                               \
    for (int q = 0; q < 3; ++q)                                     \
      GLL(gsrc[q] + (kt) * 64, smem + (buf) * 24576 + ldst[q]);     \
  } while (0)
#define CF asm volatile("" ::: "memory")
#define BAR()                          \
  do {                                 \
    CF;                                \
    __builtin_amdgcn_s_barrier();      \
    CF;                                \
  } while (0)

  // ---- ds_read bases: row = frag base + l15, slot = lq ^ ((row>>1)&3) ----
  const int so = (lq ^ ((l15 >> 1) & 3)) * 16;
  const char* Ard = smem + (wm * 64 + l15) * 64 + so;            // + buf*24576 + mi*1024
  const char* Brd = smem + 8192 + (wn * 64 + l15) * 64 + so;     // + buf*24576 + ni*1024

  f32x4 acc[4][4];
  const f32x4 z4 = {0.f, 0.f, 0.f, 0.f};
#pragma unroll
  for (int i = 0; i < 4; ++i)
#pragma unroll
    for (int n = 0; n < 4; ++n) acc[i][n] = z4;

  // Prologue: stage tile 0 into buf0.
  ISSUE(0, 0);
  asm volatile("s_waitcnt vmcnt(0)" ::: "memory");
  BAR();

#pragma unroll 2
  for (int t = 0; t < 16; ++t) {
    const int buf = t & 1;
    if (t < 15) ISSUE(buf ^ 1, t + 1);   // issue-early: lands during this tile's MFMA
    bf16x8 a[4], b[4];
#pragma unroll
    for (int i = 0; i < 4; ++i) a[i] = *(const bf16x8*)(Ard + buf * 24576 + i * 1024);
#pragma unroll
    for (int n = 0; n < 4; ++n) b[n] = *(const bf16x8*)(Brd + buf * 24576 + n * 1024);
    __builtin_amdgcn_s_setprio(1);
#pragma unroll
    for (int n = 0; n < 4; ++n)
#pragma unroll
      for (int i = 0; i < 4; ++i)
        acc[i][n] = __builtin_amdgcn_mfma_f32_16x16x32_bf16(a[i], b[n], acc[i][n], 0, 0, 0);
    __builtin_amdgcn_s_setprio(0);
    if (t < 15) asm volatile("s_waitcnt vmcnt(0)" ::: "memory");
    BAR();
  }

  // Epilogue: stage C in LDS (64 rows x 264-ushort stride) in two wm passes, 16B stores.
  ushort* cs = (ushort*)smem;
#pragma unroll
  for (int p = 0; p < 2; ++p) {
    if (p) BAR();
    if (wm == p) {
#pragma unroll
      for (int mi = 0; mi < 4; ++mi)
#pragma unroll
        for (int n = 0; n < 4; ++n) {
          const int row = mi * 16 + lq * 4;
          const int col = wn * 64 + n * 16 + l15;
          const f32x4 v = acc[mi][n];
#pragma unroll
          for (int r = 0; r < 4; ++r) cs[(row + r) * 264 + col] = f2bf(v[r]);
        }
    }
    BAR();
#pragma unroll
    for (int j = 0; j < 4; ++j) {
      const int idx = j * 512 + tid;
      const int row = idx >> 5, c = idx & 31;
      *(uint4*)(Cg + (size_t)(m0 + p * 64 + row) * 1024 + n0 + c * 8) =
          *(const uint4*)(cs + row * 264 + c * 8);
    }
  }
#undef GLL
#undef ISSUE
#undef CF
#undef BAR
}

// ---------------- K3: parity scatter + separable FIR, one (b,o) per block, 512 thr ------
// Stage1: V[kw][u][w] = sum_{kh,d} F*C[kh*3+kw][h][w], V row stride 36 (bank spread)
// Stage2: out[u][v] = (1/16) sum_{kw,d} F*V[kw][u][(v+t0+2d-1-kw)/2]
__global__ __launch_bounds__(512) void k_fir(const ushort* __restrict__ C,
                                             float* __restrict__ out) {
  const int bo = blockIdx.x;
  const int b = bo >> 9, o = bo & 511;
  __shared__ __attribute__((aligned(16))) ushort Ct[9 * 1024];
  __shared__ float V[3 * 64 * 36];
  const ushort* Cb = C + ((size_t)(b * 9) * 512 + o) * 1024;
  for (int c = threadIdx.x; c < 1152; c += 512) {
    const int tap = c >> 7, off = (c & 127) * 8;
    *(uint4*)&Ct[tap * 1024 + off] = *(const uint4*)&Cb[(size_t)tap * 524288 + off];
  }
  __syncthreads();
#pragma unroll
  for (int j = 0; j < 3; j++) {
    const int gidx = threadIdx.x + j * 512;  // (kw, u, w0/4)
    const int kw = gidx >> 9;
    const int rem = gidx & 511;
    const int u = rem >> 3;
    const int w0 = (rem & 7) * 4;
    float a0 = 0.f, a1 = 0.f, a2 = 0.f, a3 = 0.f;
#pragma unroll
    for (int kh = 0; kh < 3; kh++) {
      const int s0 = (kh + 1 + u) & 1;
#pragma unroll
      for (int d = 0; d < 2; d++) {
        const int h = (u + s0 + 2 * d - 1 - kh) >> 1;
        const bool ok = (h >= 0) & (h < 32);
        const float cf = ok ? ((s0 == d) ? 1.f : 3.f) : 0.f;
        const int hh = ok ? h : 0;
        const uint2 cv = *(const uint2*)&Ct[kh * 3072 + kw * 1024 + hh * 32 + w0];
        a0 += cf * bf2f((ushort)(cv.x & 0xffff));
        a1 += cf * bf2f((ushort)(cv.x >> 16));
        a2 += cf * bf2f((ushort)(cv.y & 0xffff));
        a3 += cf * bf2f((ushort)(cv.y >> 16));
      }
    }
    *(float4*)&V[kw * 2304 + u * 36 + w0] = make_float4(a0, a1, a2, a3);
  }
  __syncthreads();
  const size_t ob = (size_t)bo * 4096;
#pragma unroll
  for (int j = 0; j < 2; j++) {
    const int px4 = threadIdx.x + j * 512;
    const int u = px4 >> 4;
    const int v0 = (px4 & 15) * 4;
    float r[4] = {0.f, 0.f, 0.f, 0.f};
#pragma unroll
    for (int q = 0; q < 4; q++) {
      const int v = v0 + q;
#pragma unroll
      for (int kw = 0; kw < 3; kw++) {
        const int t0 = (kw + 1 + v) & 1;
#pragma unroll
        for (int d = 0; d < 2; d++) {
          const int wx = (v + t0 + 2 * d - 1 - kw) >> 1;
          const bool ok = (wx >= 0) & (wx < 32);
          const float cf = ok ? ((t0 == d) ? 1.f : 3.f) : 0.f;
          const int ww = ok ? wx : 0;
          r[q] += cf * V[kw * 2304 + u * 36 + ww];
        }
      }
      r[q] *= 0.0625f;
    }
    *(float4*)&out[ob + u * 64 + v0] = make_float4(r[0], r[1], r[2], r[3]);
  }
}

extern "C" void kernel_launch(void* const* d_in, const int* in_sizes, int n_in,
                              void* d_out, int out_size, void* d_ws, size_t ws_size,
                              hipStream_t stream) {
  (void)in_sizes; (void)n_in; (void)out_size; (void)ws_size;
  const float* x = (const float*)d_in[0];       // [8,512,32,32] fp32
  const float* styles = (const float*)d_in[1];  // [8,512] fp32
  const float* w = (const float*)d_in[2];       // [512,512,3,3] fp32
  float* out = (float*)d_out;                   // [8,512,64,64] fp32
  char* ws = (char*)d_ws;
  ushort* Wm = (ushort*)ws;                        // 37748736 B
  ushort* XT = (ushort*)(ws + 37748736);           // 8388608 B
  ushort* C = (ushort*)(ws + 37748736 + 8388608);  // 75497472 B

  k_prep<<<1024, 256, 0, stream>>>(w, styles, x, Wm, XT);
  k_gemm<<<1152, 512, 0, stream>>>(Wm, XT, C);
  k_fir<<<4096, 512, 0, stream>>>(C, out);
}

// Round 4
// 160.178 us; speedup vs baseline: 1.0206x; 1.0206x over previous
//
#include <hip/hip_runtime.h>
#include <stdint.h>

// ModulatedConv (StyleGAN2 up-conv): B=8, Cin=Cout=512, K=3, 32x32 -> 64x64, fp32 I/O.
// Pipeline (3 kernels):
//   K1 k_prep:  blocks 0..511  = dcoef + Wm[b][tap][o][i] bf16 (37.75 MB), block per o
//               blocks 512..1023 = XT[b][hw][i] bf16 (8.39 MB) transpose
//   K2 k_gemm:  tap fused into M: per batch GEMM M=4608,N=1024,K=512. 128x256 tile,
//               BK=32, 48KB LDS -> 2 blocks/CU (16 waves/CU) AND counted-vmcnt 2-deep
//               prefetch (R2 schedule + R3 occupancy), T2 swizzle, raw barriers, setprio.
//   K3 k_fir:   parity scatter + separable 4x4 FIR per (b,o), 512 thr, padded V

#define DI __device__ __forceinline__

typedef __bf16 bf16x8 __attribute__((ext_vector_type(8)));
typedef float f32x4 __attribute__((ext_vector_type(4)));

DI float bf2f(ushort u) { union { uint32_t i; float f; } v; v.i = ((uint32_t)u) << 16; return v.f; }
DI ushort f2bf(float f) {
  union { float f; uint32_t i; } v; v.f = f;
  uint32_t x = v.i;
  return (ushort)((x + 0x7FFFu + ((x >> 16) & 1u)) >> 16);  // RNE
}

#define GAIN (1.0f / 1536.0f)  // 1/sqrt(512*512*9)

// ---------------- K1: fused weight-prep (blocks 0..511) + x-transpose (512..1023) -------
__global__ __launch_bounds__(256) void k_prep(const float* __restrict__ w,
                                              const float* __restrict__ styles,
                                              const float* __restrict__ x,
                                              ushort* __restrict__ Wm,
                                              ushort* __restrict__ xt) {
  __shared__ union {
    struct { float ss[4096]; float dc[8]; float wred[4][8]; } wp;
    float tl[32][257];
  } sm;
  const int t = threadIdx.x;
  if (blockIdx.x < 512) {
    // ---- weight prep: block per o. Thread t owns i = 2t, 2t+1. ----
    const int o = blockIdx.x;
#pragma unroll
    for (int j = 0; j < 4; j++) {
      const int idx = (t + j * 256) * 4;
      *(float4*)&sm.wp.ss[idx] = *(const float4*)&styles[idx];
    }
    float wreg[18];
    const float* wp_ = w + o * 4608 + t * 18;
#pragma unroll
    for (int k = 0; k < 9; k++) {
      float2 v2 = *(const float2*)(wp_ + 2 * k);
      wreg[2 * k] = v2.x;
      wreg[2 * k + 1] = v2.y;
    }
    float q0 = 0.f, q1 = 0.f;
#pragma unroll
    for (int k = 0; k < 9; k++) {
      q0 += wreg[k] * wreg[k];
      q1 += wreg[9 + k] * wreg[9 + k];
    }
    __syncthreads();  // ss ready
    float pb[8];
#pragma unroll
    for (int b = 0; b < 8; b++) {
      float s0 = sm.wp.ss[b * 512 + 2 * t] + 1.0f;
      float s1 = sm.wp.ss[b * 512 + 2 * t + 1] + 1.0f;
      pb[b] = s0 * s0 * q0 + s1 * s1 * q1;
    }
#pragma unroll
    for (int b = 0; b < 8; b++)
#pragma unroll
      for (int off = 32; off > 0; off >>= 1) pb[b] += __shfl_down(pb[b], off, 64);
    const int wid = t >> 6, lane = t & 63;
    if (lane == 0) {
#pragma unroll
      for (int b = 0; b < 8; b++) sm.wp.wred[wid][b] = pb[b];
    }
    __syncthreads();
    if (t < 8)
      sm.wp.dc[t] = rsqrtf((sm.wp.wred[0][t] + sm.wp.wred[1][t] + sm.wp.wred[2][t] + sm.wp.wred[3][t]) *
                               (GAIN * GAIN) + 1e-8f);
    __syncthreads();
#pragma unroll
    for (int b = 0; b < 8; b++) {
      const float d = sm.wp.dc[b];
      const float s0 = GAIN * (sm.wp.ss[b * 512 + 2 * t] + 1.0f) * d;
      const float s1 = GAIN * (sm.wp.ss[b * 512 + 2 * t + 1] + 1.0f) * d;
      ushort* base = Wm + ((size_t)(b * 9) * 512 + o) * 512 + 2 * t;
#pragma unroll
      for (int tap = 0; tap < 9; tap++) {
        ushort2 val = make_ushort2(f2bf(wreg[tap] * s0), f2bf(wreg[9 + tap] * s1));
        *(ushort2*)(base + (size_t)tap * 262144) = val;
      }
    }
  } else {
    // ---- x transpose: tile 32 i x 256 hw ----
    const int idx = blockIdx.x - 512;
    const int hw0 = (idx & 3) * 256, i0 = ((idx >> 2) & 15) * 32, b = idx >> 6;
    const float* xb = x + b * (512 * 1024);
#pragma unroll
    for (int p = 0; p < 8; p++) {
      const int r = p * 4 + (t >> 6);
      const int c4 = (t & 63) * 4;
      float4 v = *(const float4*)&xb[(i0 + r) * 1024 + hw0 + c4];
      sm.tl[r][c4] = v.x; sm.tl[r][c4 + 1] = v.y; sm.tl[r][c4 + 2] = v.z; sm.tl[r][c4 + 3] = v.w;
    }
    __syncthreads();
    ushort* xtb = xt + b * (1024 * 512);
#pragma unroll
    for (int p = 0; p < 8; p++) {
      const int hw = p * 32 + (t >> 3);
      const int i4 = (t & 7) * 4;
      ushort4 v = make_ushort4(f2bf(sm.tl[i4][hw]), f2bf(sm.tl[i4 + 1][hw]),
                               f2bf(sm.tl[i4 + 2][hw]), f2bf(sm.tl[i4 + 3][hw]));
      *(ushort4*)&xtb[(hw0 + hw) * 512 + i0 + i4] = v;
    }
  }
}

// ---------------- K2: 8 x GEMM (M=4608,N=1024,K=512), C[b] = Wm[b] @ XT[b]^T ------------
// 128x256 tile, BK=32, 8 waves (2M x 4N), wave 64x64 (acc[4][4] = 64 VGPR).
// LDS 48 KiB = 2dbuf x { A[128][32k]=8KB , B[256][32k]=16KB }, row = 64 B = 4 slots.
// 2 blocks/CU (16 waves/CU = 4/SIMD; needs VGPR<=128 -> launch_bounds(512,4)):
// cross-block overlap hides barrier stalls; counted vmcnt keeps loads in flight.
// Swizzle (rule 21): LDS linear dest; source slot = (l&3)^((l>>2)&3);
// ds_read slot = lq ^ (row&3).
// Per K-tile t (stage-ahead D=2, 3 GLL/wave/tile, all hazard-checked):
//   P1: ds_read a0-3, b01; GLL B23(t+1)->buf^1 | BAR | MFMA 8 (ni0-1) | BAR
//       (B23 region of buf^1 last read P2(t-1), complete at its trailing BAR -> safe)
//   P2: ds_read b23; GLL A(t+2),B01(t+2)->buf | BAR | MFMA 8 (ni2-3) | vmcnt(2) | BAR
//       (A,B01 of buf last read P1(t), complete at P1 trailing BAR -> safe)
// FIFO/wave: ...B23(t+1) | A,B01(t+2) | gate vmcnt(2) retires all of t+1, leaves t+2's 2.
__global__ __launch_bounds__(512, 4) void k_gemm(const ushort* __restrict__ A,
                                                 const ushort* __restrict__ Bt,
                                                 ushort* __restrict__ C) {
  __shared__ __attribute__((aligned(128))) char smem[49152];
  const int id = blockIdx.x;
  const int batch = id & 7;        // XCD affinity: XT slab (1 MB) stays L2-resident
  const int rem = id >> 3;         // 0..143: mt-major (4 consecutive share A panel)
  const int mt = rem >> 2, nt = rem & 3;
  const int m0 = mt * 128, n0 = nt * 256;
  const ushort* Ag = A + (size_t)batch * (4608 * 512);
  const ushort* Bg = Bt + (size_t)batch * (1024 * 512);
  ushort* Cg = C + (size_t)batch * (4608 * 1024);

  const int tid = threadIdx.x;
  const int w = tid >> 6, lane = tid & 63;
  const int wm = w >> 2, wn = w & 3;            // wave tile: rows wm*64, cols wn*64
  const int lq = lane >> 4, l15 = lane & 15;

  // ---- staging: 24 chunks (A:8, B01:8, B23:8), 3 per wave, 16 rows/chunk ----
  const int srow = lane >> 2;                        // row within chunk (0..15)
  const int ssw = (lane & 3) ^ ((lane >> 2) & 3);    // inverse-swizzled source slot
  const int cb01 = (w >> 1) * 4 + (w & 1);           // B chunks {0,1,4,5,8,9,12,13}
  const int cb23 = cb01 + 2;                         // B chunks {2,3,6,7,10,11,14,15}
  const char* pa = (const char*)Ag + (size_t)(m0 + w * 16 + srow) * 1024 + ssw * 16;
  const char* pb01 = (const char*)Bg + (size_t)(n0 + cb01 * 16 + srow) * 1024 + ssw * 16;
  const char* pb23 = (const char*)Bg + (size_t)(n0 + cb23 * 16 + srow) * 1024 + ssw * 16;
  char* da = smem + w * 1024;
  char* db01 = smem + 8192 + cb01 * 1024;
  char* db23 = smem + 8192 + cb23 * 1024;

#define GLL(srcp, dstp)                                                                     \
  __builtin_amdgcn_global_load_lds((const __attribute__((address_space(1))) void*)(srcp),   \
                                   (__attribute__((address_space(3))) void*)(dstp), 16, 0, 0)
#define CF asm volatile("" ::: "memory")
#define BAR()                          \
  do {                                 \
    CF;                                \
    __builtin_amdgcn_s_barrier();      \
    CF;                                \
  } while (0)

  // ---- ds_read bases: row = frag base + l15, slot = lq ^ (row&3) ----
  const int so = (lq ^ (l15 & 3)) * 16;
  const char* Ard = smem + (wm * 64 + l15) * 64 + so;          // + buf*24576 + mi*1024
  const char* Brd = smem + 8192 + (wn * 64 + l15) * 64 + so;   // + buf*24576 + ni*1024

  f32x4 acc[4][4];
  const f32x4 z4 = {0.f, 0.f, 0.f, 0.f};
#pragma unroll
  for (int i = 0; i < 4; ++i)
#pragma unroll
    for (int n = 0; n < 4; ++n) acc[i][n] = z4;

  // Prologue: t0 fully into buf0; t1's A+B01 into buf1 (B23(1) staged in P1 of t=0).
  GLL(pa, da); GLL(pb01, db01); GLL(pb23, db23);
  GLL(pa + 64, da + 24576); GLL(pb01 + 64, db01 + 24576);
  asm volatile("s_waitcnt vmcnt(2)" ::: "memory");  // t0 landed; t1's 2 in flight
  BAR();

#pragma unroll
  for (int t = 0; t < 16; ++t) {
    const int buf = t & 1;
    const char* Ab = Ard + buf * 24576;
    const char* Bb = Brd + buf * 24576;
    bf16x8 a[4], bv[2], bw[2];
    // ---- P1: read a0-3 + b01; stage B23(t+1) -> other buf ----
#pragma unroll
    for (int i = 0; i < 4; ++i) a[i] = *(const bf16x8*)(Ab + i * 1024);
    bv[0] = *(const bf16x8*)(Bb);
    bv[1] = *(const bf16x8*)(Bb + 1024);
    if (t < 15) GLL(pb23 + (t + 1) * 64, db23 + (buf ^ 1) * 24576);
    BAR();
    __builtin_amdgcn_s_setprio(1);
#pragma unroll
    for (int n = 0; n < 2; ++n)
#pragma unroll
      for (int i = 0; i < 4; ++i)
        acc[i][n] = __builtin_amdgcn_mfma_f32_16x16x32_bf16(a[i], bv[n], acc[i][n], 0, 0, 0);
    __builtin_amdgcn_s_setprio(0);
    BAR();
    // ---- P2: read b23; stage A(t+2),B01(t+2) -> this buf; gate ----
    bw[0] = *(const bf16x8*)(Bb + 2048);
    bw[1] = *(const bf16x8*)(Bb + 3072);
    if (t < 14) {
      GLL(pa + (t + 2) * 64, da + buf * 24576);
      GLL(pb01 + (t + 2) * 64, db01 + buf * 24576);
    }
    BAR();
    __builtin_amdgcn_s_setprio(1);
#pragma unroll
    for (int n = 0; n < 2; ++n)
#pragma unroll
      for (int i = 0; i < 4; ++i)
        acc[i][2 + n] = __builtin_amdgcn_mfma_f32_16x16x32_bf16(a[i], bw[n], acc[i][2 + n], 0, 0, 0);
    __builtin_amdgcn_s_setprio(0);
    if (t < 14) {
      asm volatile("s_waitcnt vmcnt(2)" ::: "memory");  // t+1 landed; t+2's 2 in flight
    } else if (t == 14) {
      asm volatile("s_waitcnt vmcnt(0)" ::: "memory");  // drain: tile 15 landed
    }
    BAR();
  }

  // Epilogue: stage C in LDS (64 rows x 264-ushort stride) in two wm passes, 16B stores.
  ushort* cs = (ushort*)smem;
#pragma unroll
  for (int p = 0; p < 2; ++p) {
    if (p) BAR();
    if (wm == p) {
#pragma unroll
      for (int mi = 0; mi < 4; ++mi)
#pragma unroll
        for (int n = 0; n < 4; ++n) {
          const int row = mi * 16 + lq * 4;
          const int col = wn * 64 + n * 16 + l15;
          const f32x4 v = acc[mi][n];
#pragma unroll
          for (int r = 0; r < 4; ++r) cs[(row + r) * 264 + col] = f2bf(v[r]);
        }
    }
    BAR();
#pragma unroll
    for (int j = 0; j < 4; ++j) {
      const int idx = j * 512 + tid;
      const int row = idx >> 5, c = idx & 31;
      *(uint4*)(Cg + (size_t)(m0 + p * 64 + row) * 1024 + n0 + c * 8) =
          *(const uint4*)(cs + row * 264 + c * 8);
    }
  }
#undef GLL
#undef CF
#undef BAR
}

// ---------------- K3: parity scatter + separable FIR, one (b,o) per block, 512 thr ------
// Stage1: V[kw][u][w] = sum_{kh,d} F*C[kh*3+kw][h][w], V row stride 36 (bank spread)
// Stage2: out[u][v] = (1/16) sum_{kw,d} F*V[kw][u][(v+t0+2d-1-kw)/2]
__global__ __launch_bounds__(512) void k_fir(const ushort* __restrict__ C,
                                             float* __restrict__ out) {
  const int bo = blockIdx.x;
  const int b = bo >> 9, o = bo & 511;
  __shared__ __attribute__((aligned(16))) ushort Ct[9 * 1024];
  __shared__ float V[3 * 64 * 36];
  const ushort* Cb = C + ((size_t)(b * 9) * 512 + o) * 1024;
  for (int c = threadIdx.x; c < 1152; c += 512) {
    const int tap = c >> 7, off = (c & 127) * 8;
    *(uint4*)&Ct[tap * 1024 + off] = *(const uint4*)&Cb[(size_t)tap * 524288 + off];
  }
  __syncthreads();
#pragma unroll
  for (int j = 0; j < 3; j++) {
    const int gidx = threadIdx.x + j * 512;  // (kw, u, w0/4)
    const int kw = gidx >> 9;
    const int rem = gidx & 511;
    const int u = rem >> 3;
    const int w0 = (rem & 7) * 4;
    float a0 = 0.f, a1 = 0.f, a2 = 0.f, a3 = 0.f;
#pragma unroll
    for (int kh = 0; kh < 3; kh++) {
      const int s0 = (kh + 1 + u) & 1;
#pragma unroll
      for (int d = 0; d < 2; d++) {
        const int h = (u + s0 + 2 * d - 1 - kh) >> 1;
        const bool ok = (h >= 0) & (h < 32);
        const float cf = ok ? ((s0 == d) ? 1.f : 3.f) : 0.f;
        const int hh = ok ? h : 0;
        const uint2 cv = *(const uint2*)&Ct[kh * 3072 + kw * 1024 + hh * 32 + w0];
        a0 += cf * bf2f((ushort)(cv.x & 0xffff));
        a1 += cf * bf2f((ushort)(cv.x >> 16));
        a2 += cf * bf2f((ushort)(cv.y & 0xffff));
        a3 += cf * bf2f((ushort)(cv.y >> 16));
      }
    }
    *(float4*)&V[kw * 2304 + u * 36 + w0] = make_float4(a0, a1, a2, a3);
  }
  __syncthreads();
  const size_t ob = (size_t)bo * 4096;
#pragma unroll
  for (int j = 0; j < 2; j++) {
    const int px4 = threadIdx.x + j * 512;
    const int u = px4 >> 4;
    const int v0 = (px4 & 15) * 4;
    float r[4] = {0.f, 0.f, 0.f, 0.f};
#pragma unroll
    for (int q = 0; q < 4; q++) {
      const int v = v0 + q;
#pragma unroll
      for (int kw = 0; kw < 3; kw++) {
        const int t0 = (kw + 1 + v) & 1;
#pragma unroll
        for (int d = 0; d < 2; d++) {
          const int wx = (v + t0 + 2 * d - 1 - kw) >> 1;
          const bool ok = (wx >= 0) & (wx < 32);
          const float cf = ok ? ((t0 == d) ? 1.f : 3.f) : 0.f;
          const int ww = ok ? wx : 0;
          r[q] += cf * V[kw * 2304 + u * 36 + ww];
        }
      }
      r[q] *= 0.0625f;
    }
    *(float4*)&out[ob + u * 64 + v0] = make_float4(r[0], r[1], r[2], r[3]);
  }
}

extern "C" void kernel_launch(void* const* d_in, const int* in_sizes, int n_in,
                              void* d_out, int out_size, void* d_ws, size_t ws_size,
                              hipStream_t stream) {
  (void)in_sizes; (void)n_in; (void)out_size; (void)ws_size;
  const float* x = (const float*)d_in[0];       // [8,512,32,32] fp32
  const float* styles = (const float*)d_in[1];  // [8,512] fp32
  const float* w = (const float*)d_in[2];       // [512,512,3,3] fp32
  float* out = (float*)d_out;                   // [8,512,64,64] fp32
  char* ws = (char*)d_ws;
  ushort* Wm = (ushort*)ws;                        // 37748736 B
  ushort* XT = (ushort*)(ws + 37748736);           // 8388608 B
  ushort* C = (ushort*)(ws + 37748736 + 8388608);  // 75497472 B

  k_prep<<<1024, 256, 0, stream>>>(w, styles, x, Wm, XT);
  k_gemm<<<1152, 512, 0, stream>>>(Wm, XT, C);
  k_fir<<<4096, 512, 0, stream>>>(C, out);
}

// Round 5
// 158.192 us; speedup vs baseline: 1.0334x; 1.0126x over previous
//
#include <hip/hip_runtime.h>
#include <stdint.h>

// ModulatedConv (StyleGAN2 up-conv): B=8, Cin=Cout=512, K=3, 32x32 -> 64x64, fp32 I/O.
// Pipeline (3 kernels):
//   K1 k_prep:  blocks 0..511  = dcoef + Wm[b][tap][o][i] bf16 (37.75 MB), block per o
//               blocks 512..1023 = XT[b][hw][i] bf16 (8.39 MB) transpose
//   K2 k_gemm:  tap fused into M: per batch GEMM M=4608,N=1024,K=512. 128x256 tile,
//               BK=32, 48KB LDS -> 2 blocks/CU, counted-vmcnt 2-deep prefetch,
//               T2 swizzle with the VERIFIED-conflict-free involution ((row>>1)&3 key:
//               R3 measured 0 conflicts; R4's (row&3) key measured 4.7M = 4-way).
//   K3 k_fir:   parity scatter + separable 4x4 FIR per (b,o), 512 thr, padded V

#define DI __device__ __forceinline__

typedef __bf16 bf16x8 __attribute__((ext_vector_type(8)));
typedef float f32x4 __attribute__((ext_vector_type(4)));

DI float bf2f(ushort u) { union { uint32_t i; float f; } v; v.i = ((uint32_t)u) << 16; return v.f; }
DI ushort f2bf(float f) {
  union { float f; uint32_t i; } v; v.f = f;
  uint32_t x = v.i;
  return (ushort)((x + 0x7FFFu + ((x >> 16) & 1u)) >> 16);  // RNE
}

#define GAIN (1.0f / 1536.0f)  // 1/sqrt(512*512*9)

// ---------------- K1: fused weight-prep (blocks 0..511) + x-transpose (512..1023) -------
__global__ __launch_bounds__(256) void k_prep(const float* __restrict__ w,
                                              const float* __restrict__ styles,
                                              const float* __restrict__ x,
                                              ushort* __restrict__ Wm,
                                              ushort* __restrict__ xt) {
  __shared__ union {
    struct { float ss[4096]; float dc[8]; float wred[4][8]; } wp;
    float tl[32][257];
  } sm;
  const int t = threadIdx.x;
  if (blockIdx.x < 512) {
    // ---- weight prep: block per o. Thread t owns i = 2t, 2t+1. ----
    const int o = blockIdx.x;
#pragma unroll
    for (int j = 0; j < 4; j++) {
      const int idx = (t + j * 256) * 4;
      *(float4*)&sm.wp.ss[idx] = *(const float4*)&styles[idx];
    }
    float wreg[18];
    const float* wp_ = w + o * 4608 + t * 18;
#pragma unroll
    for (int k = 0; k < 9; k++) {
      float2 v2 = *(const float2*)(wp_ + 2 * k);
      wreg[2 * k] = v2.x;
      wreg[2 * k + 1] = v2.y;
    }
    float q0 = 0.f, q1 = 0.f;
#pragma unroll
    for (int k = 0; k < 9; k++) {
      q0 += wreg[k] * wreg[k];
      q1 += wreg[9 + k] * wreg[9 + k];
    }
    __syncthreads();  // ss ready
    float pb[8];
#pragma unroll
    for (int b = 0; b < 8; b++) {
      float s0 = sm.wp.ss[b * 512 + 2 * t] + 1.0f;
      float s1 = sm.wp.ss[b * 512 + 2 * t + 1] + 1.0f;
      pb[b] = s0 * s0 * q0 + s1 * s1 * q1;
    }
#pragma unroll
    for (int b = 0; b < 8; b++)
#pragma unroll
      for (int off = 32; off > 0; off >>= 1) pb[b] += __shfl_down(pb[b], off, 64);
    const int wid = t >> 6, lane = t & 63;
    if (lane == 0) {
#pragma unroll
      for (int b = 0; b < 8; b++) sm.wp.wred[wid][b] = pb[b];
    }
    __syncthreads();
    if (t < 8)
      sm.wp.dc[t] = rsqrtf((sm.wp.wred[0][t] + sm.wp.wred[1][t] + sm.wp.wred[2][t] + sm.wp.wred[3][t]) *
                               (GAIN * GAIN) + 1e-8f);
    __syncthreads();
#pragma unroll
    for (int b = 0; b < 8; b++) {
      const float d = sm.wp.dc[b];
      const float s0 = GAIN * (sm.wp.ss[b * 512 + 2 * t] + 1.0f) * d;
      const float s1 = GAIN * (sm.wp.ss[b * 512 + 2 * t + 1] + 1.0f) * d;
      ushort* base = Wm + ((size_t)(b * 9) * 512 + o) * 512 + 2 * t;
#pragma unroll
      for (int tap = 0; tap < 9; tap++) {
        ushort2 val = make_ushort2(f2bf(wreg[tap] * s0), f2bf(wreg[9 + tap] * s1));
        *(ushort2*)(base + (size_t)tap * 262144) = val;
      }
    }
  } else {
    // ---- x transpose: tile 32 i x 256 hw ----
    const int idx = blockIdx.x - 512;
    const int hw0 = (idx & 3) * 256, i0 = ((idx >> 2) & 15) * 32, b = idx >> 6;
    const float* xb = x + b * (512 * 1024);
#pragma unroll
    for (int p = 0; p < 8; p++) {
      const int r = p * 4 + (t >> 6);
      const int c4 = (t & 63) * 4;
      float4 v = *(const float4*)&xb[(i0 + r) * 1024 + hw0 + c4];
      sm.tl[r][c4] = v.x; sm.tl[r][c4 + 1] = v.y; sm.tl[r][c4 + 2] = v.z; sm.tl[r][c4 + 3] = v.w;
    }
    __syncthreads();
    ushort* xtb = xt + b * (1024 * 512);
#pragma unroll
    for (int p = 0; p < 8; p++) {
      const int hw = p * 32 + (t >> 3);
      const int i4 = (t & 7) * 4;
      ushort4 v = make_ushort4(f2bf(sm.tl[i4][hw]), f2bf(sm.tl[i4 + 1][hw]),
                               f2bf(sm.tl[i4 + 2][hw]), f2bf(sm.tl[i4 + 3][hw]));
      *(ushort4*)&xtb[(hw0 + hw) * 512 + i0 + i4] = v;
    }
  }
}

// ---------------- K2: 8 x GEMM (M=4608,N=1024,K=512), C[b] = Wm[b] @ XT[b]^T ------------
// 128x256 tile, BK=32, 8 waves (2M x 4N), wave 64x64 (acc[4][4] = 64 VGPR).
// LDS 48 KiB = 2dbuf x { A[128][32k]=8KB , B[256][32k]=16KB }, row = 64 B = 4 slots.
// 2 blocks/CU (16 waves/CU = 4/SIMD): cross-block overlap hides barrier stalls;
// counted vmcnt keeps loads in flight.
// Swizzle (rule 21, both sides same involution; R3-verified 0-conflict key):
//   source slot = (l&3)^((l>>3)&3)  [= q ^ ((row>>1)&3) with row = l>>2]
//   ds_read slot = lq ^ ((row>>1)&3)
// Read bank check: slot-index mod 8 = 4*l15 + (lq^((l15>>1)&3)) mod 8 -> 8 distinct
// groups x 2 lanes = 2-way = free (m136). R4's (row&3) key gave 4 groups x 4 = 4-way.
// Per K-tile t (stage-ahead D=2, 3 GLL/wave/tile, all hazard-checked):
//   P1: ds_read a0-3, b01; GLL B23(t+1)->buf^1 | BAR | MFMA 8 (ni0-1) | BAR
//   P2: ds_read b23; GLL A(t+2),B01(t+2)->buf | BAR | MFMA 8 (ni2-3) | vmcnt(2) | BAR
// FIFO/wave: ...B23(t+1) | A,B01(t+2) | gate vmcnt(2) retires all of t+1, leaves t+2's 2.
__global__ __launch_bounds__(512, 4) void k_gemm(const ushort* __restrict__ A,
                                                 const ushort* __restrict__ Bt,
                                                 ushort* __restrict__ C) {
  __shared__ __attribute__((aligned(128))) char smem[49152];
  const int id = blockIdx.x;
  const int batch = id & 7;        // XCD affinity: XT slab (1 MB) stays L2-resident
  const int rem = id >> 3;         // 0..143: mt-major (4 consecutive share A panel)
  const int mt = rem >> 2, nt = rem & 3;
  const int m0 = mt * 128, n0 = nt * 256;
  const ushort* Ag = A + (size_t)batch * (4608 * 512);
  const ushort* Bg = Bt + (size_t)batch * (1024 * 512);
  ushort* Cg = C + (size_t)batch * (4608 * 1024);

  const int tid = threadIdx.x;
  const int w = tid >> 6, lane = tid & 63;
  const int wm = w >> 2, wn = w & 3;            // wave tile: rows wm*64, cols wn*64
  const int lq = lane >> 4, l15 = lane & 15;

  // ---- staging: 24 chunks (A:8, B01:8, B23:8), 3 per wave, 16 rows/chunk ----
  const int srow = lane >> 2;                        // row within chunk (0..15)
  const int ssw = (lane & 3) ^ ((lane >> 3) & 3);    // inverse-swizzled source slot
  const int cb01 = (w >> 1) * 4 + (w & 1);           // B chunks {0,1,4,5,8,9,12,13}
  const int cb23 = cb01 + 2;                         // B chunks {2,3,6,7,10,11,14,15}
  const char* pa = (const char*)Ag + (size_t)(m0 + w * 16 + srow) * 1024 + ssw * 16;
  const char* pb01 = (const char*)Bg + (size_t)(n0 + cb01 * 16 + srow) * 1024 + ssw * 16;
  const char* pb23 = (const char*)Bg + (size_t)(n0 + cb23 * 16 + srow) * 1024 + ssw * 16;
  char* da = smem + w * 1024;
  char* db01 = smem + 8192 + cb01 * 1024;
  char* db23 = smem + 8192 + cb23 * 1024;

#define GLL(srcp, dstp)                                                                     \
  __builtin_amdgcn_global_load_lds((const __attribute__((address_space(1))) void*)(srcp),   \
                                   (__attribute__((address_space(3))) void*)(dstp), 16, 0, 0)
#define CF asm volatile("" ::: "memory")
#define BAR()                          \
  do {                                 \
    CF;                                \
    __builtin_amdgcn_s_barrier();      \
    CF;                                \
  } while (0)

  // ---- ds_read bases: row = frag base + l15, slot = lq ^ ((row>>1)&3) ----
  const int so = (lq ^ ((l15 >> 1) & 3)) * 16;
  const char* Ard = smem + (wm * 64 + l15) * 64 + so;          // + buf*24576 + mi*1024
  const char* Brd = smem + 8192 + (wn * 64 + l15) * 64 + so;   // + buf*24576 + ni*1024

  f32x4 acc[4][4];
  const f32x4 z4 = {0.f, 0.f, 0.f, 0.f};
#pragma unroll
  for (int i = 0; i < 4; ++i)
#pragma unroll
    for (int n = 0; n < 4; ++n) acc[i][n] = z4;

  // Prologue: t0 fully into buf0; t1's A+B01 into buf1 (B23(1) staged in P1 of t=0).
  GLL(pa, da); GLL(pb01, db01); GLL(pb23, db23);
  GLL(pa + 64, da + 24576); GLL(pb01 + 64, db01 + 24576);
  asm volatile("s_waitcnt vmcnt(2)" ::: "memory");  // t0 landed; t1's 2 in flight
  BAR();

#pragma unroll
  for (int t = 0; t < 16; ++t) {
    const int buf = t & 1;
    const char* Ab = Ard + buf * 24576;
    const char* Bb = Brd + buf * 24576;
    bf16x8 a[4], bv[2], bw[2];
    // ---- P1: read a0-3 + b01; stage B23(t+1) -> other buf ----
#pragma unroll
    for (int i = 0; i < 4; ++i) a[i] = *(const bf16x8*)(Ab + i * 1024);
    bv[0] = *(const bf16x8*)(Bb);
    bv[1] = *(const bf16x8*)(Bb + 1024);
    if (t < 15) GLL(pb23 + (t + 1) * 64, db23 + (buf ^ 1) * 24576);
    BAR();
    __builtin_amdgcn_s_setprio(1);
#pragma unroll
    for (int n = 0; n < 2; ++n)
#pragma unroll
      for (int i = 0; i < 4; ++i)
        acc[i][n] = __builtin_amdgcn_mfma_f32_16x16x32_bf16(a[i], bv[n], acc[i][n], 0, 0, 0);
    __builtin_amdgcn_s_setprio(0);
    BAR();
    // ---- P2: read b23; stage A(t+2),B01(t+2) -> this buf; gate ----
    bw[0] = *(const bf16x8*)(Bb + 2048);
    bw[1] = *(const bf16x8*)(Bb + 3072);
    if (t < 14) {
      GLL(pa + (t + 2) * 64, da + buf * 24576);
      GLL(pb01 + (t + 2) * 64, db01 + buf * 24576);
    }
    BAR();
    __builtin_amdgcn_s_setprio(1);
#pragma unroll
    for (int n = 0; n < 2; ++n)
#pragma unroll
      for (int i = 0; i < 4; ++i)
        acc[i][2 + n] = __builtin_amdgcn_mfma_f32_16x16x32_bf16(a[i], bw[n], acc[i][2 + n], 0, 0, 0);
    __builtin_amdgcn_s_setprio(0);
    if (t < 14) {
      asm volatile("s_waitcnt vmcnt(2)" ::: "memory");  // t+1 landed; t+2's 2 in flight
    } else if (t == 14) {
      asm volatile("s_waitcnt vmcnt(0)" ::: "memory");  // drain: tile 15 landed
    }
    BAR();
  }

  // Epilogue: stage C in LDS (64 rows x 264-ushort stride) in two wm passes, 16B stores.
  ushort* cs = (ushort*)smem;
#pragma unroll
  for (int p = 0; p < 2; ++p) {
    if (p) BAR();
    if (wm == p) {
#pragma unroll
      for (int mi = 0; mi < 4; ++mi)
#pragma unroll
        for (int n = 0; n < 4; ++n) {
          const int row = mi * 16 + lq * 4;
          const int col = wn * 64 + n * 16 + l15;
          const f32x4 v = acc[mi][n];
#pragma unroll
          for (int r = 0; r < 4; ++r) cs[(row + r) * 264 + col] = f2bf(v[r]);
        }
    }
    BAR();
#pragma unroll
    for (int j = 0; j < 4; ++j) {
      const int idx = j * 512 + tid;
      const int row = idx >> 5, c = idx & 31;
      *(uint4*)(Cg + (size_t)(m0 + p * 64 + row) * 1024 + n0 + c * 8) =
          *(const uint4*)(cs + row * 264 + c * 8);
    }
  }
#undef GLL
#undef CF
#undef BAR
}

// ---------------- K3: parity scatter + separable FIR, one (b,o) per block, 512 thr ------
// Stage1: V[kw][u][w] = sum_{kh,d} F*C[kh*3+kw][h][w], V row stride 36 (bank spread)
// Stage2: out[u][v] = (1/16) sum_{kw,d} F*V[kw][u][(v+t0+2d-1-kw)/2]
__global__ __launch_bounds__(512) void k_fir(const ushort* __restrict__ C,
                                             float* __restrict__ out) {
  const int bo = blockIdx.x;
  const int b = bo >> 9, o = bo & 511;
  __shared__ __attribute__((aligned(16))) ushort Ct[9 * 1024];
  __shared__ float V[3 * 64 * 36];
  const ushort* Cb = C + ((size_t)(b * 9) * 512 + o) * 1024;
  for (int c = threadIdx.x; c < 1152; c += 512) {
    const int tap = c >> 7, off = (c & 127) * 8;
    *(uint4*)&Ct[tap * 1024 + off] = *(const uint4*)&Cb[(size_t)tap * 524288 + off];
  }
  __syncthreads();
#pragma unroll
  for (int j = 0; j < 3; j++) {
    const int gidx = threadIdx.x + j * 512;  // (kw, u, w0/4)
    const int kw = gidx >> 9;
    const int rem = gidx & 511;
    const int u = rem >> 3;
    const int w0 = (rem & 7) * 4;
    float a0 = 0.f, a1 = 0.f, a2 = 0.f, a3 = 0.f;
#pragma unroll
    for (int kh = 0; kh < 3; kh++) {
      const int s0 = (kh + 1 + u) & 1;
#pragma unroll
      for (int d = 0; d < 2; d++) {
        const int h = (u + s0 + 2 * d - 1 - kh) >> 1;
        const bool ok = (h >= 0) & (h < 32);
        const float cf = ok ? ((s0 == d) ? 1.f : 3.f) : 0.f;
        const int hh = ok ? h : 0;
        const uint2 cv = *(const uint2*)&Ct[kh * 3072 + kw * 1024 + hh * 32 + w0];
        a0 += cf * bf2f((ushort)(cv.x & 0xffff));
        a1 += cf * bf2f((ushort)(cv.x >> 16));
        a2 += cf * bf2f((ushort)(cv.y & 0xffff));
        a3 += cf * bf2f((ushort)(cv.y >> 16));
      }
    }
    *(float4*)&V[kw * 2304 + u * 36 + w0] = make_float4(a0, a1, a2, a3);
  }
  __syncthreads();
  const size_t ob = (size_t)bo * 4096;
#pragma unroll
  for (int j = 0; j < 2; j++) {
    const int px4 = threadIdx.x + j * 512;
    const int u = px4 >> 4;
    const int v0 = (px4 & 15) * 4;
    float r[4] = {0.f, 0.f, 0.f, 0.f};
#pragma unroll
    for (int q = 0; q < 4; q++) {
      const int v = v0 + q;
#pragma unroll
      for (int kw = 0; kw < 3; kw++) {
        const int t0 = (kw + 1 + v) & 1;
#pragma unroll
        for (int d = 0; d < 2; d++) {
          const int wx = (v + t0 + 2 * d - 1 - kw) >> 1;
          const bool ok = (wx >= 0) & (wx < 32);
          const float cf = ok ? ((t0 == d) ? 1.f : 3.f) : 0.f;
          const int ww = ok ? wx : 0;
          r[q] += cf * V[kw * 2304 + u * 36 + ww];
        }
      }
      r[q] *= 0.0625f;
    }
    *(float4*)&out[ob + u * 64 + v0] = make_float4(r[0], r[1], r[2], r[3]);
  }
}

extern "C" void kernel_launch(void* const* d_in, const int* in_sizes, int n_in,
                              void* d_out, int out_size, void* d_ws, size_t ws_size,
                              hipStream_t stream) {
  (void)in_sizes; (void)n_in; (void)out_size; (void)ws_size;
  const float* x = (const float*)d_in[0];       // [8,512,32,32] fp32
  const float* styles = (const float*)d_in[1];  // [8,512] fp32
  const float* w = (const float*)d_in[2];       // [512,512,3,3] fp32
  float* out = (float*)d_out;                   // [8,512,64,64] fp32
  char* ws = (char*)d_ws;
  ushort* Wm = (ushort*)ws;                        // 37748736 B
  ushort* XT = (ushort*)(ws + 37748736);           // 8388608 B
  ushort* C = (ushort*)(ws + 37748736 + 8388608);  // 75497472 B

  k_prep<<<1024, 256, 0, stream>>>(w, styles, x, Wm, XT);
  k_gemm<<<1152, 512, 0, stream>>>(Wm, XT, C);
  k_fir<<<4096, 512, 0, stream>>>(C, out);
}